// Round 6
// baseline (247.211 us; speedup 1.0000x reference)
//
#include <hip/hip_runtime.h>
#include <math.h>

#define H 2048
#define E 64
#define MR 16        // rows per block
#define NCH 16       // 128-wide k chunks
#define LR 136       // LDS row stride in f16 (128 + 8 pad; 272 B rows, 16B-aligned)

typedef _Float16 half8  __attribute__((ext_vector_type(8)));
typedef _Float16 half4h __attribute__((ext_vector_type(4)));
typedef float    f32x4  __attribute__((ext_vector_type(4)));

#define MFMA16(A,B,C) __builtin_amdgcn_mfma_f32_16x16x32_f16(A,B,C,0,0,0)

// ws layout: Bh[H*E f16] | Bl[H*E f16] | csum[E f32] | bsum[E f32]

// Fused prep: pack W' = lnw*W into MFMA B-fragment layout (hi/lo f16 planes,
// lo scaled by 2048)  +  per-expert csum/bsum reductions. Both parts are the
// verbatim R3-verified bodies; both use grid=64.
__global__ __launch_bounds__(256) void prep_fused(const float* __restrict__ W,
        const float* __restrict__ lnw, const float* __restrict__ lnb,
        _Float16* __restrict__ Bh, _Float16* __restrict__ Bl,
        float* __restrict__ csum, float* __restrict__ bsum) {
    // ---- pack part ----
    {
        int idx  = blockIdx.x * 256 + threadIdx.x;      // 0..16383
        int lane = idx & 63;
        int e  = ((idx >> 6) & 3) * 16 + (lane & 15);
        int k0 = (idx >> 8) * 32 + ((lane >> 4) << 3);
        half8 hh, ll;
        #pragma unroll
        for (int j = 0; j < 8; ++j) {
            float wf = lnw[k0 + j] * W[e * H + k0 + j];
            _Float16 h = (_Float16)wf;
            _Float16 l = (_Float16)((wf - (float)h) * 2048.0f);
            hh[j] = h; ll[j] = l;
        }
        *(half8*)&Bh[(long)idx * 8] = hh;
        *(half8*)&Bl[(long)idx * 8] = ll;
    }
    // ---- sums part (expert = blockIdx.x) ----
    {
        __shared__ float rc[256], rb[256];
        int e = blockIdx.x, t = threadIdx.x;
        float cs = 0.f, bs = 0.f;
        #pragma unroll
        for (int j = 0; j < 8; ++j) {
            int k = t + j * 256;
            float w = W[e * H + k];
            cs += lnw[k] * w;
            bs += lnb[k] * w;
        }
        rc[t] = cs; rb[t] = bs;
        __syncthreads();
        for (int s = 128; s > 0; s >>= 1) {
            if (t < s) { rc[t] += rc[t + s]; rb[t] += rb[t + s]; }
            __syncthreads();
        }
        if (t == 0) { csum[e] = rc[0]; bsum[e] = rb[0]; }
    }
}

// Two-plane router (R3-verified numerics, bit-identical accumulation order)
// with W prefetched 1 chunk ahead into named register sets (WA*/WB*) and X
// prefetched 2 chunks ahead (vbA/vbB). Pure scheduling change vs R3.
__global__ __launch_bounds__(256, 4) void router_kernel(
    const float* __restrict__ X, const _Float16* __restrict__ Bh,
    const _Float16* __restrict__ Bl, const float* __restrict__ csum,
    const float* __restrict__ bsum, float* __restrict__ out, int nRows)
{
    __shared__ __align__(16) _Float16 Xh[2][MR][LR];   // 8,704 B
    __shared__ __align__(16) _Float16 Xl[2][MR][LR];   // 8,704 B
    __shared__ float C2[MR][E + 4];                    // 4,352 B
    __shared__ float mu_s[MR], rs_s[MR];
    // ~21.9 KB LDS

    const int t    = threadIdx.x;
    const int lane = t & 63;
    const int et   = t >> 6;                 // wave -> expert tile (16 experts)
    const int q    = lane >> 4;
    const int ln16 = lane & 15;
    const int rowR = t >> 4;                 // staging/stats row 0..15 (16 thr/row)
    const int cS   = t & 15;                 // float4 col group within chunk
    const long rowBase = (long)blockIdx.x * MR;
    const long iOff = (long)nRows * 2;
    const long lOff = (long)nRows * 4;

    const float4* Xrow = (const float4*)X + (rowBase + rowR) * 512;

    float sacc = 0.f, qacc = 0.f;            // LN stats, fixed row per thread

    f32x4 acc0 = (f32x4)0.f;
    f32x4 acc1 = (f32x4)0.f;

    auto convert = [&](const float4* vb, int buf) {
        #pragma unroll
        for (int j = 0; j < 2; ++j) {
            float4 v = vb[j];
            sacc += v.x + v.y + v.z + v.w;
            qacc += v.x * v.x + v.y * v.y + v.z * v.z + v.w * v.w;
            _Float16 h0 = (_Float16)v.x, h1 = (_Float16)v.y,
                     h2 = (_Float16)v.z, h3 = (_Float16)v.w;
            _Float16 l0 = (_Float16)((v.x - (float)h0) * 2048.f);
            _Float16 l1 = (_Float16)((v.y - (float)h1) * 2048.f);
            _Float16 l2 = (_Float16)((v.z - (float)h2) * 2048.f);
            _Float16 l3 = (_Float16)((v.w - (float)h3) * 2048.f);
            half4h hh = {h0, h1, h2, h3};
            half4h ll = {l0, l1, l2, l3};
            int col = (cS + j * 16) * 4;
            *(half4h*)&Xh[buf][rowR][col] = hh;
            *(half4h*)&Xl[buf][rowR][col] = ll;
        }
    };
    auto loadW = [&](half8* Wh, half8* Wl, int c) {
        #pragma unroll
        for (int ks = 0; ks < 4; ++ks) {
            int bo = (((c * 4 + ks) * 4 + et) * 64 + lane) * 8;
            Wh[ks] = *(const half8*)&Bh[bo];
            Wl[ks] = *(const half8*)&Bl[bo];
        }
    };
    auto loadX = [&](float4* vb, int c) {
        #pragma unroll
        for (int j = 0; j < 2; ++j)
            vb[j] = Xrow[c * 32 + cS + j * 16];
    };
    auto mfmaC = [&](const half8* Wh, const half8* Wl, int buf) {
        #pragma unroll
        for (int ks = 0; ks < 4; ++ks) {
            half8 Ah = *(const half8*)&Xh[buf][ln16][ks * 32 + q * 8];
            half8 Al = *(const half8*)&Xl[buf][ln16][ks * 32 + q * 8];
            acc0 = MFMA16(Ah, Wh[ks], acc0);
            acc1 = MFMA16(Ah, Wl[ks], acc1);
            acc1 = MFMA16(Al, Wh[ks], acc1);
        }
    };

    half8 WAh[4], WAl[4], WBh[4], WBl[4];
    float4 vbA[2], vbB[2];

    // prologue: X(0) direct-convert, W(0) -> WA, X(1) -> vbA
    {
        float4 v0[2];
        loadX(v0, 0);
        loadW(WAh, WAl, 0);
        loadX(vbA, 1);
        convert(v0, 0);
    }
    __syncthreads();

    for (int c = 0; c < NCH; c += 2) {
        // ---- even chunk c: buf 0, W in WA; vbA holds X(c+1) ----
        loadW(WBh, WBl, c + 1);
        if (c + 2 < NCH) loadX(vbB, c + 2);
        mfmaC(WAh, WAl, 0);
        convert(vbA, 1);
        __syncthreads();

        // ---- odd chunk c+1: buf 1, W in WB; vbB holds X(c+2) ----
        if (c + 2 < NCH) loadW(WAh, WAl, c + 2);
        if (c + 3 < NCH) loadX(vbA, c + 3);
        mfmaC(WBh, WBl, 1);
        if (c + 2 < NCH) convert(vbB, 0);
        __syncthreads();
    }

    // ---- finalize LN stats (16 lanes per row: bits 0-3 of lane) ----
    {
        float s = sacc, qq = qacc;
        #pragma unroll
        for (int d = 1; d < 16; d <<= 1) {
            s  += __shfl_xor(s, d);
            qq += __shfl_xor(qq, d);
        }
        if (cS == 0) {
            float mu  = s * (1.f / H);
            float var = qq * (1.f / H) - mu * mu;
            mu_s[rowR] = mu;
            rs_s[rowR] = rsqrtf(var + 1e-5f);
        }
    }
    __syncthreads();

    // ---- epilogue: combine splits, LN rank-1 correction, clip, write logits ----
    {
        int n = et * 16 + ln16;
        float cs = csum[n], bs = bsum[n];
        #pragma unroll
        for (int reg = 0; reg < 4; ++reg) {
            int r = q * 4 + reg;
            float raw = acc0[reg] + acc1[reg] * (1.f / 2048.f);
            float lg = rs_s[r] * (raw - mu_s[r] * cs) + bs;
            lg = fminf(fmaxf(lg, -10.f), 10.f);
            out[lOff + (rowBase + r) * 64 + n] = lg;
            C2[r][n] = lg;
        }
    }
    __syncthreads();

    // ---- softmax + top2: wave et handles rows et*4 .. et*4+3 ----
    #pragma unroll
    for (int rr = 0; rr < 4; ++rr) {
        int r = et * 4 + rr;
        float l = C2[r][lane];
        float m = l;
        #pragma unroll
        for (int d = 1; d < 64; d <<= 1) m = fmaxf(m, __shfl_xor(m, d));
        float p = __expf(l - m);
        float ssum = p;
        #pragma unroll
        for (int d = 1; d < 64; d <<= 1) ssum += __shfl_xor(ssum, d);
        float prob = fminf(fmaxf(p / ssum, 1e-4f), 1.0f);

        float v1 = prob; int i1 = lane;
        #pragma unroll
        for (int d = 1; d < 64; d <<= 1) {
            float ov = __shfl_xor(v1, d);
            int   oi = __shfl_xor(i1, d);
            if (ov > v1 || (ov == v1 && oi < i1)) { v1 = ov; i1 = oi; }
        }
        float v2 = (lane == i1) ? -1.f : prob; int i2 = lane;
        #pragma unroll
        for (int d = 1; d < 64; d <<= 1) {
            float ov = __shfl_xor(v2, d);
            int   oi = __shfl_xor(i2, d);
            if (ov > v2 || (ov == v2 && oi < i2)) { v2 = ov; i2 = oi; }
        }
        if (lane == 0) {
            float ps = fmaxf(v1 + v2, 1e-4f);
            long rg_ = rowBase + r;
            out[rg_ * 2 + 0] = v1 / ps;
            out[rg_ * 2 + 1] = v2 / ps;
            out[iOff + rg_ * 2 + 0] = (float)i1;
            out[iOff + rg_ * 2 + 1] = (float)i2;
        }
    }
}

extern "C" void kernel_launch(void* const* d_in, const int* in_sizes, int n_in,
                              void* d_out, int out_size, void* d_ws, size_t ws_size,
                              hipStream_t stream) {
    const float* X   = (const float*)d_in[0];
    const float* lnw = (const float*)d_in[1];
    const float* lnb = (const float*)d_in[2];
    const float* W   = (const float*)d_in[3];
    float* outp = (float*)d_out;

    _Float16* Bh = (_Float16*)d_ws;
    _Float16* Bl = Bh + H * E;
    float* csum  = (float*)(Bl + H * E);
    float* bsum  = csum + E;

    int N = in_sizes[0] / H;                 // 16384 rows

    prep_fused<<<64, 256, 0, stream>>>(W, lnw, lnb, Bh, Bl, csum, bsum);
    router_kernel<<<N / MR, 256, 0, stream>>>(X, Bh, Bl, csum, bsum, outp, N);
}

// Round 7
// 244.608 us; speedup vs baseline: 1.0106x; 1.0106x over previous
//
#include <hip/hip_runtime.h>
#include <math.h>

#define H 2048
#define E 64
#define MR 16        // rows per block
#define NCH 16       // 128-wide k chunks
#define LR 136       // LDS row stride in f16 (128 + 8 pad; 272 B rows, 16B-aligned)

typedef _Float16 half8  __attribute__((ext_vector_type(8)));
typedef _Float16 half4h __attribute__((ext_vector_type(4)));
typedef float    f32x4  __attribute__((ext_vector_type(4)));

#define MFMA16(A,B,C) __builtin_amdgcn_mfma_f32_16x16x32_f16(A,B,C,0,0,0)

// ws layout: Bh[H*E f16] | Bl[H*E f16] | csum[E f32] | bsum[E f32]

// Fused prep: pack W' = lnw*W into MFMA B-fragment layout (hi/lo f16 planes,
// lo scaled by 2048)  +  per-expert csum/bsum reductions. Grid = 64.
__global__ __launch_bounds__(256) void prep_fused(const float* __restrict__ W,
        const float* __restrict__ lnw, const float* __restrict__ lnb,
        _Float16* __restrict__ Bh, _Float16* __restrict__ Bl,
        float* __restrict__ csum, float* __restrict__ bsum) {
    // ---- pack part ----
    {
        int idx  = blockIdx.x * 256 + threadIdx.x;      // 0..16383
        int lane = idx & 63;
        int e  = ((idx >> 6) & 3) * 16 + (lane & 15);
        int k0 = (idx >> 8) * 32 + ((lane >> 4) << 3);
        half8 hh, ll;
        #pragma unroll
        for (int j = 0; j < 8; ++j) {
            float wf = lnw[k0 + j] * W[e * H + k0 + j];
            _Float16 h = (_Float16)wf;
            _Float16 l = (_Float16)((wf - (float)h) * 2048.0f);
            hh[j] = h; ll[j] = l;
        }
        *(half8*)&Bh[(long)idx * 8] = hh;
        *(half8*)&Bl[(long)idx * 8] = ll;
    }
    // ---- sums part (expert = blockIdx.x) ----
    {
        __shared__ float rc[256], rb[256];
        int e = blockIdx.x, t = threadIdx.x;
        float cs = 0.f, bs = 0.f;
        #pragma unroll
        for (int j = 0; j < 8; ++j) {
            int k = t + j * 256;
            float w = W[e * H + k];
            cs += lnw[k] * w;
            bs += lnb[k] * w;
        }
        rc[t] = cs; rb[t] = bs;
        __syncthreads();
        for (int s = 128; s > 0; s >>= 1) {
            if (t < s) { rc[t] += rc[t + s]; rb[t] += rb[t + s]; }
            __syncthreads();
        }
        if (t == 0) { csum[e] = rc[0]; bsum[e] = rb[0]; }
    }
}

// Two-plane router, R3-verified numeric order, with W prefetched 1 chunk
// ahead and X 2 chunks ahead into INDIVIDUALLY NAMED registers (macros, no
// arrays-through-pointers -> no scratch; R6 lesson).
__global__ __launch_bounds__(256, 4) void router_kernel(
    const float* __restrict__ X, const _Float16* __restrict__ Bh,
    const _Float16* __restrict__ Bl, const float* __restrict__ csum,
    const float* __restrict__ bsum, float* __restrict__ out, int nRows)
{
    __shared__ __align__(16) _Float16 Xh[2][MR][LR];   // 8,704 B
    __shared__ __align__(16) _Float16 Xl[2][MR][LR];   // 8,704 B
    __shared__ float C2[MR][E + 4];                    // 4,352 B
    __shared__ float mu_s[MR], rs_s[MR];
    // ~21.9 KB LDS

    const int t    = threadIdx.x;
    const int lane = t & 63;
    const int et   = t >> 6;                 // wave -> expert tile (16 experts)
    const int q    = lane >> 4;
    const int ln16 = lane & 15;
    const int rowR = t >> 4;                 // staging/stats row 0..15 (16 thr/row)
    const int cS   = t & 15;                 // float4 col group within chunk
    const long rowBase = (long)blockIdx.x * MR;
    const long iOff = (long)nRows * 2;
    const long lOff = (long)nRows * 4;

    const float4* Xrow = (const float4*)X + (rowBase + rowR) * 512;

    float sacc = 0.f, qacc = 0.f;            // LN stats, fixed row per thread
    f32x4 acc0 = (f32x4)0.f;
    f32x4 acc1 = (f32x4)0.f;

    half8 WAh0, WAh1, WAh2, WAh3, WAl0, WAl1, WAl2, WAl3;
    half8 WBh0, WBh1, WBh2, WBh3, WBl0, WBl1, WBl2, WBl3;
    float4 vA0, vA1, vB0, vB1;

// issue 8 W-fragment loads for chunk c into named set S (hi+lo per ks)
#define LOADW(S, c) { \
    int b0_ = ((((c) * 4 + 0) * 4 + et) * 64 + lane) * 8; \
    S##h0 = *(const half8*)&Bh[b0_];  S##l0 = *(const half8*)&Bl[b0_]; \
    int b1_ = ((((c) * 4 + 1) * 4 + et) * 64 + lane) * 8; \
    S##h1 = *(const half8*)&Bh[b1_];  S##l1 = *(const half8*)&Bl[b1_]; \
    int b2_ = ((((c) * 4 + 2) * 4 + et) * 64 + lane) * 8; \
    S##h2 = *(const half8*)&Bh[b2_];  S##l2 = *(const half8*)&Bl[b2_]; \
    int b3_ = ((((c) * 4 + 3) * 4 + et) * 64 + lane) * 8; \
    S##h3 = *(const half8*)&Bh[b3_];  S##l3 = *(const half8*)&Bl[b3_]; }

// issue 2 X float4 loads for chunk c into named pair S
#define LOADX(S, c) { \
    S##0 = Xrow[(c) * 32 + cS]; \
    S##1 = Xrow[(c) * 32 + cS + 16]; }

// hi/lo split one float4 V into Xh/Xl at half-col JCOL*4 (stats in R3 order)
#define CVT1(V, JCOL, buf) { \
    float4 v_ = (V); \
    sacc += v_.x + v_.y + v_.z + v_.w; \
    qacc += v_.x * v_.x + v_.y * v_.y + v_.z * v_.z + v_.w * v_.w; \
    _Float16 h0_ = (_Float16)v_.x, h1_ = (_Float16)v_.y, \
             h2_ = (_Float16)v_.z, h3_ = (_Float16)v_.w; \
    _Float16 l0_ = (_Float16)((v_.x - (float)h0_) * 2048.f); \
    _Float16 l1_ = (_Float16)((v_.y - (float)h1_) * 2048.f); \
    _Float16 l2_ = (_Float16)((v_.z - (float)h2_) * 2048.f); \
    _Float16 l3_ = (_Float16)((v_.w - (float)h3_) * 2048.f); \
    half4h hh_ = {h0_, h1_, h2_, h3_}; \
    half4h ll_ = {l0_, l1_, l2_, l3_}; \
    *(half4h*)&Xh[buf][rowR][(JCOL) * 4] = hh_; \
    *(half4h*)&Xl[buf][rowR][(JCOL) * 4] = ll_; }

#define CONVERT(S, buf) { CVT1(S##0, cS, buf) CVT1(S##1, cS + 16, buf) }

// one ks step: 3 MFMAs in the verified order
#define MFMAKS(Wh_, Wl_, buf, ks) { \
    half8 Ah_ = *(const half8*)&Xh[buf][ln16][(ks) * 32 + q * 8]; \
    half8 Al_ = *(const half8*)&Xl[buf][ln16][(ks) * 32 + q * 8]; \
    acc0 = MFMA16(Ah_, Wh_, acc0); \
    acc1 = MFMA16(Ah_, Wl_, acc1); \
    acc1 = MFMA16(Al_, Wh_, acc1); }

#define MFMAC(S, buf) { \
    MFMAKS(S##h0, S##l0, buf, 0) MFMAKS(S##h1, S##l1, buf, 1) \
    MFMAKS(S##h2, S##l2, buf, 2) MFMAKS(S##h3, S##l3, buf, 3) }

    // prologue: X(0) direct-convert, W(0) -> WA set, X(1) -> vA pair
    {
        float4 v00 = Xrow[cS];
        float4 v01 = Xrow[cS + 16];
        LOADW(WA, 0)
        LOADX(vA, 1)
        CVT1(v00, cS, 0)
        CVT1(v01, cS + 16, 0)
    }
    __syncthreads();

    for (int c = 0; c < NCH; c += 2) {
        // ---- even chunk c: buf 0, W in WA; vA holds X(c+1) ----
        LOADW(WB, c + 1)
        if (c + 2 < NCH) LOADX(vB, c + 2)
        MFMAC(WA, 0)
        CONVERT(vA, 1)
        __syncthreads();

        // ---- odd chunk c+1: buf 1, W in WB; vB holds X(c+2) ----
        if (c + 2 < NCH) LOADW(WA, c + 2)
        if (c + 3 < NCH) LOADX(vA, c + 3)
        MFMAC(WB, 1)
        if (c + 2 < NCH) CONVERT(vB, 0)
        __syncthreads();
    }

    // ---- finalize LN stats (16 lanes per row: bits 0-3 of lane) ----
    {
        float s = sacc, qq = qacc;
        #pragma unroll
        for (int d = 1; d < 16; d <<= 1) {
            s  += __shfl_xor(s, d);
            qq += __shfl_xor(qq, d);
        }
        if (cS == 0) {
            float mu  = s * (1.f / H);
            float var = qq * (1.f / H) - mu * mu;
            mu_s[rowR] = mu;
            rs_s[rowR] = rsqrtf(var + 1e-5f);
        }
    }
    __syncthreads();

    // ---- epilogue: combine splits, LN rank-1 correction, clip, write logits ----
    {
        int n = et * 16 + ln16;
        float cs = csum[n], bs = bsum[n];
        #pragma unroll
        for (int reg = 0; reg < 4; ++reg) {
            int r = q * 4 + reg;
            float raw = acc0[reg] + acc1[reg] * (1.f / 2048.f);
            float lg = rs_s[r] * (raw - mu_s[r] * cs) + bs;
            lg = fminf(fmaxf(lg, -10.f), 10.f);
            out[lOff + (rowBase + r) * 64 + n] = lg;
            C2[r][n] = lg;
        }
    }
    __syncthreads();

    // ---- softmax + top2: wave et handles rows et*4 .. et*4+3 ----
    #pragma unroll
    for (int rr = 0; rr < 4; ++rr) {
        int r = et * 4 + rr;
        float l = C2[r][lane];
        float m = l;
        #pragma unroll
        for (int d = 1; d < 64; d <<= 1) m = fmaxf(m, __shfl_xor(m, d));
        float p = __expf(l - m);
        float ssum = p;
        #pragma unroll
        for (int d = 1; d < 64; d <<= 1) ssum += __shfl_xor(ssum, d);
        float prob = fminf(fmaxf(p / ssum, 1e-4f), 1.0f);

        float v1 = prob; int i1 = lane;
        #pragma unroll
        for (int d = 1; d < 64; d <<= 1) {
            float ov = __shfl_xor(v1, d);
            int   oi = __shfl_xor(i1, d);
            if (ov > v1 || (ov == v1 && oi < i1)) { v1 = ov; i1 = oi; }
        }
        float v2 = (lane == i1) ? -1.f : prob; int i2 = lane;
        #pragma unroll
        for (int d = 1; d < 64; d <<= 1) {
            float ov = __shfl_xor(v2, d);
            int   oi = __shfl_xor(i2, d);
            if (ov > v2 || (ov == v2 && oi < i2)) { v2 = ov; i2 = oi; }
        }
        if (lane == 0) {
            float ps = fmaxf(v1 + v2, 1e-4f);
            long rg_ = rowBase + r;
            out[rg_ * 2 + 0] = v1 / ps;
            out[rg_ * 2 + 1] = v2 / ps;
            out[iOff + rg_ * 2 + 0] = (float)i1;
            out[iOff + rg_ * 2 + 1] = (float)i2;
        }
    }
}

extern "C" void kernel_launch(void* const* d_in, const int* in_sizes, int n_in,
                              void* d_out, int out_size, void* d_ws, size_t ws_size,
                              hipStream_t stream) {
    const float* X   = (const float*)d_in[0];
    const float* lnw = (const float*)d_in[1];
    const float* lnb = (const float*)d_in[2];
    const float* W   = (const float*)d_in[3];
    float* outp = (float*)d_out;

    _Float16* Bh = (_Float16*)d_ws;
    _Float16* Bl = Bh + H * E;
    float* csum  = (float*)(Bl + H * E);
    float* bsum  = csum + E;

    int N = in_sizes[0] / H;                 // 16384 rows

    prep_fused<<<64, 256, 0, stream>>>(W, lnw, lnb, Bh, Bl, csum, bsum);
    router_kernel<<<N / MR, 256, 0, stream>>>(X, Bh, Bl, csum, bsum, outp, N);
}

// Round 8
// 214.645 us; speedup vs baseline: 1.1517x; 1.1396x over previous
//
#include <hip/hip_runtime.h>
#include <math.h>

#define H 2048
#define E 64
#define MR 16        // rows per block
#define NCH 16       // 128-wide k chunks
#define LR 136       // LDS row stride in f16 (128 + 8 pad; 272 B rows, 16B-aligned)

typedef _Float16 half8  __attribute__((ext_vector_type(8)));
typedef _Float16 half4h __attribute__((ext_vector_type(4)));
typedef float    f32x4  __attribute__((ext_vector_type(4)));

#define MFMA16(A,B,C) __builtin_amdgcn_mfma_f32_16x16x32_f16(A,B,C,0,0,0)

// ws layout: Bh[H*E f16] | Bl[H*E f16] | csum[E f32] | bsum[E f32]

// Fused prep: pack W' = lnw*W into MFMA B-fragment layout (hi/lo f16 planes,
// lo scaled by 2048)  +  per-expert csum/bsum reductions. Grid = 64.
// Verified numerics-neutral in R6/R7 (absmax unchanged).
__global__ __launch_bounds__(256) void prep_fused(const float* __restrict__ W,
        const float* __restrict__ lnw, const float* __restrict__ lnb,
        _Float16* __restrict__ Bh, _Float16* __restrict__ Bl,
        float* __restrict__ csum, float* __restrict__ bsum) {
    // ---- pack part ----
    {
        int idx  = blockIdx.x * 256 + threadIdx.x;      // 0..16383
        int lane = idx & 63;
        int e  = ((idx >> 6) & 3) * 16 + (lane & 15);
        int k0 = (idx >> 8) * 32 + ((lane >> 4) << 3);
        half8 hh, ll;
        #pragma unroll
        for (int j = 0; j < 8; ++j) {
            float wf = lnw[k0 + j] * W[e * H + k0 + j];
            _Float16 h = (_Float16)wf;
            _Float16 l = (_Float16)((wf - (float)h) * 2048.0f);
            hh[j] = h; ll[j] = l;
        }
        *(half8*)&Bh[(long)idx * 8] = hh;
        *(half8*)&Bl[(long)idx * 8] = ll;
    }
    // ---- sums part (expert = blockIdx.x) ----
    {
        __shared__ float rc[256], rb[256];
        int e = blockIdx.x, t = threadIdx.x;
        float cs = 0.f, bs = 0.f;
        #pragma unroll
        for (int j = 0; j < 8; ++j) {
            int k = t + j * 256;
            float w = W[e * H + k];
            cs += lnw[k] * w;
            bs += lnb[k] * w;
        }
        rc[t] = cs; rb[t] = bs;
        __syncthreads();
        for (int s = 128; s > 0; s >>= 1) {
            if (t < s) { rc[t] += rc[t + s]; rb[t] += rb[t + s]; }
            __syncthreads();
        }
        if (t == 0) { csum[e] = rc[0]; bsum[e] = rb[0]; }
    }
}

// R3-verified router + X prefetch extended to 2 chunks ahead.
// W loads stay ITERATION-SCOPED (R3's promotable pattern; the R6/R7 scratch
// came from loop-carried W register sets). Only 4 named float4 (16 VGPRs)
// are loop-carried. Per-thread accumulation/stat order bit-identical to R3.
__global__ __launch_bounds__(256, 4) void router_kernel(
    const float* __restrict__ X, const _Float16* __restrict__ Bh,
    const _Float16* __restrict__ Bl, const float* __restrict__ csum,
    const float* __restrict__ bsum, float* __restrict__ out, int nRows)
{
    __shared__ __align__(16) _Float16 Xh[2][MR][LR];   // 8,704 B
    __shared__ __align__(16) _Float16 Xl[2][MR][LR];   // 8,704 B
    __shared__ float C2[MR][E + 4];                    // 4,352 B
    __shared__ float mu_s[MR], rs_s[MR];
    // ~21.9 KB LDS

    const int t    = threadIdx.x;
    const int lane = t & 63;
    const int et   = t >> 6;                 // wave -> expert tile (16 experts)
    const int q    = lane >> 4;
    const int ln16 = lane & 15;
    const int rowR = t >> 4;                 // staging/stats row 0..15 (16 thr/row)
    const int cS   = t & 15;                 // float4 col group within chunk
    const long rowBase = (long)blockIdx.x * MR;
    const long iOff = (long)nRows * 2;
    const long lOff = (long)nRows * 4;

    const float4* Xrow = (const float4*)X + (rowBase + rowR) * 512;

    float sacc = 0.f, qacc = 0.f;            // LN stats, fixed row per thread
    f32x4 acc0 = (f32x4)0.f;
    f32x4 acc1 = (f32x4)0.f;

    // convert two float4 (by value) into buf; stats in R3 order (v0 then v1)
    auto convert = [&](float4 v0_, float4 v1_, int buf) {
        #pragma unroll
        for (int j = 0; j < 2; ++j) {
            float4 v = j ? v1_ : v0_;
            sacc += v.x + v.y + v.z + v.w;
            qacc += v.x * v.x + v.y * v.y + v.z * v.z + v.w * v.w;
            _Float16 h0 = (_Float16)v.x, h1 = (_Float16)v.y,
                     h2 = (_Float16)v.z, h3 = (_Float16)v.w;
            _Float16 l0 = (_Float16)((v.x - (float)h0) * 2048.f);
            _Float16 l1 = (_Float16)((v.y - (float)h1) * 2048.f);
            _Float16 l2 = (_Float16)((v.z - (float)h2) * 2048.f);
            _Float16 l3 = (_Float16)((v.w - (float)h3) * 2048.f);
            half4h hh = {h0, h1, h2, h3};
            half4h ll = {l0, l1, l2, l3};
            int col = (cS + j * 16) * 4;
            *(half4h*)&Xh[buf][rowR][col] = hh;
            *(half4h*)&Xl[buf][rowR][col] = ll;
        }
    };
    // iteration-scoped W load + MFMA for one chunk (R3 pattern, verbatim order)
    auto loadW = [&](half8* Wh, half8* Wl, int c) {
        #pragma unroll
        for (int ks = 0; ks < 4; ++ks) {
            int bo = (((c * 4 + ks) * 4 + et) * 64 + lane) * 8;
            Wh[ks] = *(const half8*)&Bh[bo];
            Wl[ks] = *(const half8*)&Bl[bo];
        }
    };
    auto mfmaC = [&](const half8* Wh, const half8* Wl, int buf) {
        #pragma unroll
        for (int ks = 0; ks < 4; ++ks) {
            half8 Ah = *(const half8*)&Xh[buf][ln16][ks * 32 + q * 8];
            half8 Al = *(const half8*)&Xl[buf][ln16][ks * 32 + q * 8];
            acc0 = MFMA16(Ah, Wh[ks], acc0);
            acc1 = MFMA16(Ah, Wl[ks], acc1);
            acc1 = MFMA16(Al, Wh[ks], acc1);
        }
    };

    // loop-carried X prefetch: 2 chunks deep, individually named
    float4 vA0, vA1, vB0, vB1;

    // prologue: X(0) load+convert into buf0, X(1) -> vA pair
    {
        float4 v00 = Xrow[cS];
        float4 v01 = Xrow[cS + 16];
        vA0 = Xrow[32 + cS];
        vA1 = Xrow[32 + cS + 16];
        convert(v00, v01, 0);
    }
    __syncthreads();

    for (int c = 0; c < NCH; c += 2) {
        // ---- even chunk c: MFMA buf0; vA holds X(c+1); issue X(c+2)->vB ----
        {
            half8 Wh[4], Wl[4];
            loadW(Wh, Wl, c);
            if (c + 2 < NCH) {
                vB0 = Xrow[(c + 2) * 32 + cS];
                vB1 = Xrow[(c + 2) * 32 + cS + 16];
            }
            mfmaC(Wh, Wl, 0);
            convert(vA0, vA1, 1);
        }
        __syncthreads();

        // ---- odd chunk c+1: MFMA buf1; vB holds X(c+2); issue X(c+3)->vA ----
        {
            half8 Wh[4], Wl[4];
            loadW(Wh, Wl, c + 1);
            if (c + 3 < NCH) {
                vA0 = Xrow[(c + 3) * 32 + cS];
                vA1 = Xrow[(c + 3) * 32 + cS + 16];
            }
            mfmaC(Wh, Wl, 1);
            if (c + 2 < NCH) convert(vB0, vB1, 0);
        }
        __syncthreads();
    }

    // ---- finalize LN stats (16 lanes per row: bits 0-3 of lane) ----
    {
        float s = sacc, qq = qacc;
        #pragma unroll
        for (int d = 1; d < 16; d <<= 1) {
            s  += __shfl_xor(s, d);
            qq += __shfl_xor(qq, d);
        }
        if (cS == 0) {
            float mu  = s * (1.f / H);
            float var = qq * (1.f / H) - mu * mu;
            mu_s[rowR] = mu;
            rs_s[rowR] = rsqrtf(var + 1e-5f);
        }
    }
    __syncthreads();

    // ---- epilogue: combine splits, LN rank-1 correction, clip, write logits ----
    {
        int n = et * 16 + ln16;
        float cs = csum[n], bs = bsum[n];
        #pragma unroll
        for (int reg = 0; reg < 4; ++reg) {
            int r = q * 4 + reg;
            float raw = acc0[reg] + acc1[reg] * (1.f / 2048.f);
            float lg = rs_s[r] * (raw - mu_s[r] * cs) + bs;
            lg = fminf(fmaxf(lg, -10.f), 10.f);
            out[lOff + (rowBase + r) * 64 + n] = lg;
            C2[r][n] = lg;
        }
    }
    __syncthreads();

    // ---- softmax + top2: wave et handles rows et*4 .. et*4+3 ----
    #pragma unroll
    for (int rr = 0; rr < 4; ++rr) {
        int r = et * 4 + rr;
        float l = C2[r][lane];
        float m = l;
        #pragma unroll
        for (int d = 1; d < 64; d <<= 1) m = fmaxf(m, __shfl_xor(m, d));
        float p = __expf(l - m);
        float ssum = p;
        #pragma unroll
        for (int d = 1; d < 64; d <<= 1) ssum += __shfl_xor(ssum, d);
        float prob = fminf(fmaxf(p / ssum, 1e-4f), 1.0f);

        float v1 = prob; int i1 = lane;
        #pragma unroll
        for (int d = 1; d < 64; d <<= 1) {
            float ov = __shfl_xor(v1, d);
            int   oi = __shfl_xor(i1, d);
            if (ov > v1 || (ov == v1 && oi < i1)) { v1 = ov; i1 = oi; }
        }
        float v2 = (lane == i1) ? -1.f : prob; int i2 = lane;
        #pragma unroll
        for (int d = 1; d < 64; d <<= 1) {
            float ov = __shfl_xor(v2, d);
            int   oi = __shfl_xor(i2, d);
            if (ov > v2 || (ov == v2 && oi < i2)) { v2 = ov; i2 = oi; }
        }
        if (lane == 0) {
            float ps = fmaxf(v1 + v2, 1e-4f);
            long rg_ = rowBase + r;
            out[rg_ * 2 + 0] = v1 / ps;
            out[rg_ * 2 + 1] = v2 / ps;
            out[iOff + rg_ * 2 + 0] = (float)i1;
            out[iOff + rg_ * 2 + 1] = (float)i2;
        }
    }
}

extern "C" void kernel_launch(void* const* d_in, const int* in_sizes, int n_in,
                              void* d_out, int out_size, void* d_ws, size_t ws_size,
                              hipStream_t stream) {
    const float* X   = (const float*)d_in[0];
    const float* lnw = (const float*)d_in[1];
    const float* lnb = (const float*)d_in[2];
    const float* W   = (const float*)d_in[3];
    float* outp = (float*)d_out;

    _Float16* Bh = (_Float16*)d_ws;
    _Float16* Bl = Bh + H * E;
    float* csum  = (float*)(Bl + H * E);
    float* bsum  = csum + E;

    int N = in_sizes[0] / H;                 // 16384 rows

    prep_fused<<<64, 256, 0, stream>>>(W, lnw, lnb, Bh, Bl, csum, bsum);
    router_kernel<<<N / MR, 256, 0, stream>>>(X, Bh, Bl, csum, bsum, outp, N);
}